// Round 1
// baseline (298.080 us; speedup 1.0000x reference)
//
#include <hip/hip_runtime.h>
#include <stdint.h>
#include <stddef.h>

#define EMB 1024
#define HEADS 16
#define HDIM 64
#define NTOK 16384

typedef __attribute__((ext_vector_type(8))) short short8;
typedef __attribute__((ext_vector_type(4))) float floatx4;

__device__ __forceinline__ unsigned short f2bf(float f) {
    union { float f; unsigned int u; } v; v.f = f;
    unsigned int u = v.u;
    unsigned int r = (u + 0x7fffu + ((u >> 16) & 1u)) >> 16;
    return (unsigned short)r;
}
__device__ __forceinline__ float bf2f(unsigned short s) {
    union { unsigned int u; float f; } v; v.u = ((unsigned int)s) << 16;
    return v.f;
}

__device__ __forceinline__ void gload16(const void* g, void* l) {
    __builtin_amdgcn_global_load_lds(
        (const __attribute__((address_space(1))) void*)g,
        (__attribute__((address_space(3))) void*)l, 16, 0, 0);
}

// ---------------- fp32 -> bf16 conversion (vectorized) ----------------
__global__ void cvt_kernel(const float* __restrict__ in,
                           unsigned short* __restrict__ out, int n4) {
    int idx = blockIdx.x * blockDim.x + threadIdx.x;
    int stride = gridDim.x * blockDim.x;
    for (int i = idx; i < n4; i += stride) {
        float4 f = reinterpret_cast<const float4*>(in)[i];
        ushort4 o;
        o.x = f2bf(f.x); o.y = f2bf(f.y); o.z = f2bf(f.z); o.w = f2bf(f.w);
        reinterpret_cast<ushort4*>(out)[i] = o;
    }
}

// ---------------- bf16 GEMM: C[M][Nc] = A[M][K] * B[Nc][K]^T + bias ----------------
// 128x128 tile, BK=32, 4 waves (each 64x64 = 4x4 fragments of 16x16x32 MFMA)
__device__ __forceinline__ void store_val(float* C, size_t idx, float v) { C[idx] = v; }
__device__ __forceinline__ void store_val(unsigned short* C, size_t idx, float v) { C[idx] = f2bf(v); }

template<typename OUT_T>
__global__ __launch_bounds__(256)
void gemm_bt(const unsigned short* __restrict__ A,
             const unsigned short* __restrict__ B,
             const float* __restrict__ bias,
             OUT_T* __restrict__ C,
             int M, int Nc, int K)
{
    const int tid  = threadIdx.x;
    const int wave = tid >> 6;
    const int lane = tid & 63;
    const int m0 = blockIdx.x * 128;
    const int n0 = blockIdx.y * 128;

    __shared__ unsigned short As[128 * 32];
    __shared__ unsigned short Bs[128 * 32];

    floatx4 acc[4][4];
#pragma unroll
    for (int i = 0; i < 4; ++i)
#pragma unroll
        for (int j = 0; j < 4; ++j)
            acc[i][j] = (floatx4){0.f, 0.f, 0.f, 0.f};

    const int wm = (wave >> 1) * 64;
    const int wn = (wave & 1) * 64;
    const int rr = lane & 15;
    const int kr = (lane >> 4) * 8;

    const int srow = tid >> 2;        // 0..63
    const int scol = (tid & 3) * 8;   // 0,8,16,24

    const unsigned short* Abase  = A + (size_t)(m0 + srow) * K + scol;
    const unsigned short* Abase2 = A + (size_t)(m0 + 64 + srow) * K + scol;
    const unsigned short* Bbase  = B + (size_t)(n0 + srow) * K + scol;
    const unsigned short* Bbase2 = B + (size_t)(n0 + 64 + srow) * K + scol;

    unsigned short* Adst  = &As[(size_t)tid * 8];
    unsigned short* Adst2 = &As[(size_t)(tid + 256) * 8];
    unsigned short* Bdst  = &Bs[(size_t)tid * 8];
    unsigned short* Bdst2 = &Bs[(size_t)(tid + 256) * 8];

    for (int kt = 0; kt < K; kt += 32) {
        __syncthreads();
        gload16(Abase + kt,  Adst);
        gload16(Abase2 + kt, Adst2);
        gload16(Bbase + kt,  Bdst);
        gload16(Bbase2 + kt, Bdst2);
        __syncthreads();

        short8 af[4], bfr[4];
#pragma unroll
        for (int i = 0; i < 4; ++i)
            af[i] = *reinterpret_cast<const short8*>(&As[(wm + i * 16 + rr) * 32 + kr]);
#pragma unroll
        for (int j = 0; j < 4; ++j)
            bfr[j] = *reinterpret_cast<const short8*>(&Bs[(wn + j * 16 + rr) * 32 + kr]);
#pragma unroll
        for (int i = 0; i < 4; ++i)
#pragma unroll
            for (int j = 0; j < 4; ++j)
                acc[i][j] = __builtin_amdgcn_mfma_f32_16x16x32_bf16(af[i], bfr[j], acc[i][j], 0, 0, 0);
    }

    const int cn = lane & 15;
    const int cm = (lane >> 4) * 4;
#pragma unroll
    for (int j = 0; j < 4; ++j) {
        const int col = n0 + wn + j * 16 + cn;
        const float bv = bias[col];
#pragma unroll
        for (int i = 0; i < 4; ++i) {
            const int row = m0 + wm + i * 16 + cm;
#pragma unroll
            for (int r = 0; r < 4; ++r) {
                float v = acc[i][j][r] + bv;
                store_val(C, (size_t)(row + r) * Nc + col, v);
            }
        }
    }
}

// ---------------- per-token 16-head attention (wave per token) ----------------
// scores[h][g] = q[h].k[g]/8 ; softmax over g ; out[h][d] = sum_g attn[h][g] v[g][d]
#define ROWP 72   // padded row stride (ushorts) to avoid LDS bank conflicts

__global__ __launch_bounds__(256)
void attn_kernel(const unsigned short* __restrict__ Q,
                 const unsigned short* __restrict__ K,
                 const unsigned short* __restrict__ V,
                 unsigned short* __restrict__ O)
{
    const int wave = threadIdx.x >> 6;
    const int lane = threadIdx.x & 63;
    const int n = blockIdx.x * 4 + wave;

    __shared__ unsigned short lq[4][16 * ROWP];
    __shared__ unsigned short lk[4][16 * ROWP];
    __shared__ unsigned short lv[4][16 * ROWP];
    __shared__ float lp[4][256];

    {
        const unsigned short* gq = Q + (size_t)n * EMB;
        const unsigned short* gk = K + (size_t)n * EMB;
        const unsigned short* gv = V + (size_t)n * EMB;
        for (int t = lane; t < 128; t += 64) {
            int r = t >> 3, c = t & 7;
            *reinterpret_cast<short8*>(&lq[wave][r * ROWP + c * 8]) =
                *reinterpret_cast<const short8*>(gq + t * 8);
            *reinterpret_cast<short8*>(&lk[wave][r * ROWP + c * 8]) =
                *reinterpret_cast<const short8*>(gk + t * 8);
            *reinterpret_cast<short8*>(&lv[wave][r * ROWP + c * 8]) =
                *reinterpret_cast<const short8*>(gv + t * 8);
        }
    }
    __syncthreads();

    const int g = lane & 15;
    const int a = lane >> 4;

    // k row g -> fp32 regs
    float kf[64];
#pragma unroll
    for (int c2 = 0; c2 < 8; ++c2) {
        short8 kv = *reinterpret_cast<const short8*>(&lk[wave][g * ROWP + c2 * 8]);
#pragma unroll
        for (int e = 0; e < 8; ++e) kf[c2 * 8 + e] = bf2f((unsigned short)kv[e]);
    }

#pragma unroll
    for (int i = 0; i < 4; ++i) {
        const int h = i * 4 + a;
        float s = 0.f;
#pragma unroll
        for (int c2 = 0; c2 < 8; ++c2) {
            short8 qv = *reinterpret_cast<const short8*>(&lq[wave][h * ROWP + c2 * 8]);
#pragma unroll
            for (int e = 0; e < 8; ++e)
                s = fmaf(bf2f((unsigned short)qv[e]), kf[c2 * 8 + e], s);
        }
        s *= 0.125f;  // 1/sqrt(64)

        float m = s;
#pragma unroll
        for (int o = 1; o < 16; o <<= 1) m = fmaxf(m, __shfl_xor(m, o, 64));
        float p = expf(s - m);
        float sum = p;
#pragma unroll
        for (int o = 1; o < 16; o <<= 1) sum += __shfl_xor(sum, o, 64);
        lp[wave][h * 16 + g] = p / sum;
    }
    __syncthreads();

    // output: lane -> h = lane>>2, d-block = (lane&3)*16
    const int h = lane >> 2;
    const int db = (lane & 3) * 16;
    float o[16];
#pragma unroll
    for (int e = 0; e < 16; ++e) o[e] = 0.f;

    for (int g2 = 0; g2 < 16; ++g2) {
        const float pw = lp[wave][h * 16 + g2];
        short8 v0 = *reinterpret_cast<const short8*>(&lv[wave][g2 * ROWP + db]);
        short8 v1 = *reinterpret_cast<const short8*>(&lv[wave][g2 * ROWP + db + 8]);
#pragma unroll
        for (int e = 0; e < 8; ++e) {
            o[e]     = fmaf(pw, bf2f((unsigned short)v0[e]), o[e]);
            o[8 + e] = fmaf(pw, bf2f((unsigned short)v1[e]), o[8 + e]);
        }
    }

    short8 o0, o1;
#pragma unroll
    for (int e = 0; e < 8; ++e) {
        o0[e] = (short)f2bf(o[e]);
        o1[e] = (short)f2bf(o[8 + e]);
    }
    unsigned short* dst = O + (size_t)n * EMB + h * 64 + db;
    *reinterpret_cast<short8*>(dst) = o0;
    *reinterpret_cast<short8*>(dst + 8) = o1;
}

// ---------------- launch ----------------
extern "C" void kernel_launch(void* const* d_in, const int* in_sizes, int n_in,
                              void* d_out, int out_size, void* d_ws, size_t ws_size,
                              hipStream_t stream)
{
    const float* src = (const float*)d_in[0];
    const float* Wq  = (const float*)d_in[1];
    const float* bq  = (const float*)d_in[2];
    const float* Wk  = (const float*)d_in[3];
    const float* bk  = (const float*)d_in[4];
    const float* Wv  = (const float*)d_in[5];
    const float* bv  = (const float*)d_in[6];
    const float* Wo  = (const float*)d_in[7];
    const float* bo  = (const float*)d_in[8];
    float* out = (float*)d_out;

    unsigned short* ws = (unsigned short*)d_ws;
    unsigned short* src_bf = ws;
    unsigned short* wq_bf  = src_bf + (size_t)NTOK * EMB;
    unsigned short* wk_bf  = wq_bf + (size_t)EMB * EMB;
    unsigned short* wv_bf  = wk_bf + (size_t)EMB * EMB;
    unsigned short* wo_bf  = wv_bf + (size_t)EMB * EMB;
    unsigned short* qb     = wo_bf + (size_t)EMB * EMB;
    unsigned short* kb     = qb + (size_t)NTOK * EMB;
    unsigned short* vb     = kb + (size_t)NTOK * EMB;
    unsigned short* ab     = vb + (size_t)NTOK * EMB;

    cvt_kernel<<<2048, 256, 0, stream>>>(src, src_bf, NTOK * EMB / 4);
    cvt_kernel<<<512, 256, 0, stream>>>(Wq, wq_bf, EMB * EMB / 4);
    cvt_kernel<<<512, 256, 0, stream>>>(Wk, wk_bf, EMB * EMB / 4);
    cvt_kernel<<<512, 256, 0, stream>>>(Wv, wv_bf, EMB * EMB / 4);
    cvt_kernel<<<512, 256, 0, stream>>>(Wo, wo_bf, EMB * EMB / 4);

    dim3 grid(NTOK / 128, EMB / 128);  // (128, 8)
    gemm_bt<unsigned short><<<grid, 256, 0, stream>>>(src_bf, wq_bf, bq, qb, NTOK, EMB, EMB);
    gemm_bt<unsigned short><<<grid, 256, 0, stream>>>(src_bf, wk_bf, bk, kb, NTOK, EMB, EMB);
    gemm_bt<unsigned short><<<grid, 256, 0, stream>>>(src_bf, wv_bf, bv, vb, NTOK, EMB, EMB);

    attn_kernel<<<NTOK / 4, 256, 0, stream>>>(qb, kb, vb, ab);

    gemm_bt<float><<<grid, 256, 0, stream>>>(ab, wo_bf, bo, out, NTOK, EMB, EMB);
}

// Round 2
// 223.655 us; speedup vs baseline: 1.3328x; 1.3328x over previous
//
#include <hip/hip_runtime.h>
#include <stdint.h>
#include <stddef.h>

#define EMB 1024
#define NTOK 16384

typedef __attribute__((ext_vector_type(8))) short short8;
typedef __attribute__((ext_vector_type(4))) float floatx4;

__device__ __forceinline__ unsigned short f2bf(float f) {
    union { float f; unsigned int u; } v; v.f = f;
    unsigned int u = v.u;
    unsigned int r = (u + 0x7fffu + ((u >> 16) & 1u)) >> 16;
    return (unsigned short)r;
}
__device__ __forceinline__ float bf2f(unsigned short s) {
    union { unsigned int u; float f; } v; v.u = ((unsigned int)s) << 16;
    return v.f;
}

__device__ __forceinline__ void gload16(const void* g, void* l) {
    __builtin_amdgcn_global_load_lds(
        (const __attribute__((address_space(1))) void*)g,
        (__attribute__((address_space(3))) void*)l, 16, 0, 0);
}

// ---------------- fp32 -> bf16 conversion (vectorized) ----------------
__global__ void cvt_kernel(const float* __restrict__ in,
                           unsigned short* __restrict__ out, int n4) {
    int idx = blockIdx.x * blockDim.x + threadIdx.x;
    int stride = gridDim.x * blockDim.x;
    for (int i = idx; i < n4; i += stride) {
        float4 f = reinterpret_cast<const float4*>(in)[i];
        ushort4 o;
        o.x = f2bf(f.x); o.y = f2bf(f.y); o.z = f2bf(f.z); o.w = f2bf(f.w);
        reinterpret_cast<ushort4*>(out)[i] = o;
    }
}

__global__ void bias_cat_kernel(const float* __restrict__ b0,
                                const float* __restrict__ b1,
                                const float* __restrict__ b2,
                                float* __restrict__ out) {
    int i = blockIdx.x * blockDim.x + threadIdx.x;   // 3072 threads total
    float v = (i < 1024) ? b0[i] : (i < 2048 ? b1[i - 1024] : b2[i - 2048]);
    out[i] = v;
}

// ---------------- 256x256 8-phase bf16 GEMM:  C = A[M][K] * B[Nc][K]^T + bias ----------------
// BK=64, 512 threads (8 waves, 2M x 4N), LDS 128 KB double-buffered.
// LDS layout (ushort elems): buf(2) x { A:[kh(2)][256][32] , B:[kh(2)][256][32] }
//   A(b,kh) = b*32768 + kh*8192 ;  B(b,kh) = b*32768 + 16384 + kh*8192
// Within a region, 8-elem (16B) k-slots are XOR-swizzled by ((row>>1)&3):
//   stored slot s holds logical slot s ^ ((row>>1)&3)  (involution; applied on the
//   GLOBAL source address during staging, and on the LDS read address).
__device__ __forceinline__ void store_val(float* C, size_t idx, float v) { C[idx] = v; }
__device__ __forceinline__ void store_val(unsigned short* C, size_t idx, float v) { C[idx] = f2bf(v); }

template<typename OUT_T>
__global__ __launch_bounds__(512, 2)
void gemm256(const unsigned short* __restrict__ A,
             const unsigned short* __restrict__ B,
             const float* __restrict__ bias,
             OUT_T* __restrict__ C,
             int K, int Nc, int grid_m)
{
    __shared__ unsigned short lds[65536];  // 128 KB

    // XCD-aware bijective swizzle (nwg % 8 == 0 for all our grids)
    const int bid = blockIdx.x;
    const int cpx = gridDim.x >> 3;
    const int wg  = (bid & 7) * cpx + (bid >> 3);
    const int m0 = (wg % grid_m) * 256;
    const int n0 = (wg / grid_m) * 256;

    const int tid  = threadIdx.x;
    const int lane = tid & 63;
    const int wid  = tid >> 6;
    const int wm = (wid >> 2) * 128;   // wave rows (0 / 128)
    const int wn = (wid & 3) * 64;     // wave cols (0/64/128/192)
    const int rr = lane & 15;
    // swizzled k-slot offset for fragment reads (lane-constant, elems)
    const int klo = (((lane >> 4) ^ ((rr >> 1) & 3)) << 3);

    // staging: 2 x 16B loads per thread per region (region = 256 rows x 32 k)
    const unsigned short* pA[2];
    const unsigned short* pB[2];
    int ldst[2];
#pragma unroll
    for (int l = 0; l < 2; ++l) {
        const int P16  = l * 512 + tid;            // 16B-block index within region
        const int rowS = P16 >> 2;                 // 0..255
        const int colel = (((P16 & 3) ^ ((rowS >> 1) & 3)) << 3); // swizzled src col
        pA[l] = A + (size_t)(m0 + rowS) * K + colel;
        pB[l] = B + (size_t)(n0 + rowS) * K + colel;
        ldst[l] = P16 * 8;                         // linear LDS dest (elems)
    }

    floatx4 acc[8][4];
#pragma unroll
    for (int i = 0; i < 8; ++i)
#pragma unroll
        for (int j = 0; j < 4; ++j)
            acc[i][j] = (floatx4){0.f, 0.f, 0.f, 0.f};

    const int NT = K >> 6;   // K / 64

    // ---- prologue: stage tile 0 into buf 0, drain, barrier ----
#pragma unroll
    for (int l = 0; l < 2; ++l) {
        gload16(pA[l],      &lds[0     + ldst[l]]);   // A kh0
        gload16(pA[l] + 32, &lds[8192  + ldst[l]]);   // A kh1
        gload16(pB[l],      &lds[16384 + ldst[l]]);   // B kh0
        gload16(pB[l] + 32, &lds[24576 + ldst[l]]);   // B kh1
    }
    asm volatile("s_waitcnt vmcnt(0)" ::: "memory");
    asm volatile("s_barrier" ::: "memory");

    for (int t = 0; t < NT; ++t) {
        const int cur = (t & 1) * 32768;
        const int nxt = cur ^ 32768;
        const int ktn = (t + 1 < NT) ? (t + 1) * 64 : 0;  // wrapped prefetch on last iter

        short8 bf[4];

        // ================= phase 0: kh0, row-half 0 =================
        {
            short8 af[4];
            const unsigned short* la = &lds[cur + (wm + rr) * 32 + klo];
#pragma unroll
            for (int i = 0; i < 4; ++i) af[i] = *reinterpret_cast<const short8*>(la + i * 512);
            const unsigned short* lb = &lds[cur + 16384 + (wn + rr) * 32 + klo];
#pragma unroll
            for (int j = 0; j < 4; ++j) bf[j] = *reinterpret_cast<const short8*>(lb + j * 512);
            gload16(pA[0] + ktn, &lds[nxt + ldst[0]]);          // stage A-kh0(next)
            gload16(pA[1] + ktn, &lds[nxt + ldst[1]]);
            asm volatile("s_barrier" ::: "memory");
            __builtin_amdgcn_s_setprio(1);
#pragma unroll
            for (int j = 0; j < 4; ++j)
#pragma unroll
                for (int i = 0; i < 4; ++i)
                    acc[i][j] = __builtin_amdgcn_mfma_f32_16x16x32_bf16(af[i], bf[j], acc[i][j], 0, 0, 0);
            __builtin_amdgcn_s_setprio(0);
            asm volatile("s_barrier" ::: "memory");
        }
        // ================= phase 1: kh0, row-half 1 =================
        {
            short8 af[4];
            const unsigned short* la = &lds[cur + (wm + 64 + rr) * 32 + klo];
#pragma unroll
            for (int i = 0; i < 4; ++i) af[i] = *reinterpret_cast<const short8*>(la + i * 512);
            gload16(pB[0] + ktn, &lds[nxt + 16384 + ldst[0]]);  // stage B-kh0(next)
            gload16(pB[1] + ktn, &lds[nxt + 16384 + ldst[1]]);
            asm volatile("s_barrier" ::: "memory");
            __builtin_amdgcn_s_setprio(1);
#pragma unroll
            for (int j = 0; j < 4; ++j)
#pragma unroll
                for (int i = 0; i < 4; ++i)
                    acc[4 + i][j] = __builtin_amdgcn_mfma_f32_16x16x32_bf16(af[i], bf[j], acc[4 + i][j], 0, 0, 0);
            __builtin_amdgcn_s_setprio(0);
            // counted wait: guards current tile's kh1 regions (issued prev iter ph2/ph3);
            // leaves this iter's ph0/ph1 stages (4 loads) in flight.
            asm volatile("s_waitcnt vmcnt(4)" ::: "memory");
            asm volatile("s_barrier" ::: "memory");
        }
        // ================= phase 2: kh1, row-half 0 =================
        {
            short8 af[4];
            const unsigned short* la = &lds[cur + 8192 + (wm + rr) * 32 + klo];
#pragma unroll
            for (int i = 0; i < 4; ++i) af[i] = *reinterpret_cast<const short8*>(la + i * 512);
            const unsigned short* lb = &lds[cur + 24576 + (wn + rr) * 32 + klo];
#pragma unroll
            for (int j = 0; j < 4; ++j) bf[j] = *reinterpret_cast<const short8*>(lb + j * 512);
            gload16(pA[0] + ktn + 32, &lds[nxt + 8192 + ldst[0]]);   // stage A-kh1(next)
            gload16(pA[1] + ktn + 32, &lds[nxt + 8192 + ldst[1]]);
            asm volatile("s_barrier" ::: "memory");
            __builtin_amdgcn_s_setprio(1);
#pragma unroll
            for (int j = 0; j < 4; ++j)
#pragma unroll
                for (int i = 0; i < 4; ++i)
                    acc[i][j] = __builtin_amdgcn_mfma_f32_16x16x32_bf16(af[i], bf[j], acc[i][j], 0, 0, 0);
            __builtin_amdgcn_s_setprio(0);
            asm volatile("s_barrier" ::: "memory");
        }
        // ================= phase 3: kh1, row-half 1 =================
        {
            short8 af[4];
            const unsigned short* la = &lds[cur + 8192 + (wm + 64 + rr) * 32 + klo];
#pragma unroll
            for (int i = 0; i < 4; ++i) af[i] = *reinterpret_cast<const short8*>(la + i * 512);
            gload16(pB[0] + ktn + 32, &lds[nxt + 24576 + ldst[0]]);  // stage B-kh1(next)
            gload16(pB[1] + ktn + 32, &lds[nxt + 24576 + ldst[1]]);
            asm volatile("s_barrier" ::: "memory");
            __builtin_amdgcn_s_setprio(1);
#pragma unroll
            for (int j = 0; j < 4; ++j)
#pragma unroll
                for (int i = 0; i < 4; ++i)
                    acc[4 + i][j] = __builtin_amdgcn_mfma_f32_16x16x32_bf16(af[i], bf[j], acc[4 + i][j], 0, 0, 0);
            __builtin_amdgcn_s_setprio(0);
            // counted wait: guards next tile's kh0 regions (issued this iter ph0/ph1);
            // leaves ph2/ph3 stages (4 loads) in flight.
            asm volatile("s_waitcnt vmcnt(4)" ::: "memory");
            asm volatile("s_barrier" ::: "memory");
        }
    }

    // ---- epilogue: C write + bias ----
    const int cn  = lane & 15;
    const int cm4 = (lane >> 4) * 4;
    float bv[4];
#pragma unroll
    for (int j = 0; j < 4; ++j) bv[j] = bias[n0 + wn + j * 16 + cn];
#pragma unroll
    for (int ai = 0; ai < 8; ++ai) {
        const int row = m0 + wm + (ai >> 2) * 64 + (ai & 3) * 16 + cm4;
#pragma unroll
        for (int j = 0; j < 4; ++j) {
            const int col = n0 + wn + j * 16 + cn;
#pragma unroll
            for (int r = 0; r < 4; ++r)
                store_val(C, (size_t)(row + r) * Nc + col, acc[ai][j][r] + bv[j]);
        }
    }
}

// ---------------- per-token 16-head attention (wave per token) ----------------
#define ROWP 72

__global__ __launch_bounds__(256)
void attn_kernel(const unsigned short* __restrict__ QKV,  // [N][3072] fused q|k|v
                 unsigned short* __restrict__ O)
{
    const int wave = threadIdx.x >> 6;
    const int lane = threadIdx.x & 63;
    const int n = blockIdx.x * 4 + wave;

    __shared__ unsigned short lq[4][16 * ROWP];
    __shared__ unsigned short lk[4][16 * ROWP];
    __shared__ unsigned short lv[4][16 * ROWP];
    __shared__ float lp[4][256];

    {
        const unsigned short* gq = QKV + (size_t)n * 3072;
        const unsigned short* gk = gq + 1024;
        const unsigned short* gv = gq + 2048;
        for (int t = lane; t < 128; t += 64) {
            int r = t >> 3, c = t & 7;
            *reinterpret_cast<short8*>(&lq[wave][r * ROWP + c * 8]) =
                *reinterpret_cast<const short8*>(gq + t * 8);
            *reinterpret_cast<short8*>(&lk[wave][r * ROWP + c * 8]) =
                *reinterpret_cast<const short8*>(gk + t * 8);
            *reinterpret_cast<short8*>(&lv[wave][r * ROWP + c * 8]) =
                *reinterpret_cast<const short8*>(gv + t * 8);
        }
    }
    __syncthreads();

    const int g = lane & 15;
    const int a = lane >> 4;

    float kf[64];
#pragma unroll
    for (int c2 = 0; c2 < 8; ++c2) {
        short8 kv = *reinterpret_cast<const short8*>(&lk[wave][g * ROWP + c2 * 8]);
#pragma unroll
        for (int e = 0; e < 8; ++e) kf[c2 * 8 + e] = bf2f((unsigned short)kv[e]);
    }

#pragma unroll
    for (int i = 0; i < 4; ++i) {
        const int h = i * 4 + a;
        float s = 0.f;
#pragma unroll
        for (int c2 = 0; c2 < 8; ++c2) {
            short8 qv = *reinterpret_cast<const short8*>(&lq[wave][h * ROWP + c2 * 8]);
#pragma unroll
            for (int e = 0; e < 8; ++e)
                s = fmaf(bf2f((unsigned short)qv[e]), kf[c2 * 8 + e], s);
        }
        s *= 0.125f;

        float m = s;
#pragma unroll
        for (int o = 1; o < 16; o <<= 1) m = fmaxf(m, __shfl_xor(m, o, 64));
        float p = expf(s - m);
        float sum = p;
#pragma unroll
        for (int o = 1; o < 16; o <<= 1) sum += __shfl_xor(sum, o, 64);
        lp[wave][h * 16 + g] = p / sum;
    }
    __syncthreads();

    const int h = lane >> 2;
    const int db = (lane & 3) * 16;
    float o[16];
#pragma unroll
    for (int e = 0; e < 16; ++e) o[e] = 0.f;

    for (int g2 = 0; g2 < 16; ++g2) {
        const float pw = lp[wave][h * 16 + g2];
        short8 v0 = *reinterpret_cast<const short8*>(&lv[wave][g2 * ROWP + db]);
        short8 v1 = *reinterpret_cast<const short8*>(&lv[wave][g2 * ROWP + db + 8]);
#pragma unroll
        for (int e = 0; e < 8; ++e) {
            o[e]     = fmaf(pw, bf2f((unsigned short)v0[e]), o[e]);
            o[8 + e] = fmaf(pw, bf2f((unsigned short)v1[e]), o[8 + e]);
        }
    }

    short8 o0, o1;
#pragma unroll
    for (int e = 0; e < 8; ++e) {
        o0[e] = (short)f2bf(o[e]);
        o1[e] = (short)f2bf(o[8 + e]);
    }
    unsigned short* dst = O + (size_t)n * EMB + h * 64 + db;
    *reinterpret_cast<short8*>(dst) = o0;
    *reinterpret_cast<short8*>(dst + 8) = o1;
}

// ---------------- launch ----------------
extern "C" void kernel_launch(void* const* d_in, const int* in_sizes, int n_in,
                              void* d_out, int out_size, void* d_ws, size_t ws_size,
                              hipStream_t stream)
{
    const float* src = (const float*)d_in[0];
    const float* Wq  = (const float*)d_in[1];
    const float* bq  = (const float*)d_in[2];
    const float* Wk  = (const float*)d_in[3];
    const float* bk  = (const float*)d_in[4];
    const float* Wv  = (const float*)d_in[5];
    const float* bv  = (const float*)d_in[6];
    const float* Wo  = (const float*)d_in[7];
    const float* bo  = (const float*)d_in[8];
    float* out = (float*)d_out;

    unsigned short* ws = (unsigned short*)d_ws;
    unsigned short* src_bf = ws;                                      // 16384*1024
    unsigned short* wqkv   = src_bf + (size_t)NTOK * EMB;             // 3*1024*1024 (Wq|Wk|Wv)
    unsigned short* wo_bf  = wqkv + (size_t)3 * EMB * EMB;            // 1024*1024
    unsigned short* qkv    = wo_bf + (size_t)EMB * EMB;               // 16384*3072
    unsigned short* ab     = qkv + (size_t)NTOK * 3 * EMB;            // 16384*1024
    float* bias_cat        = (float*)(ab + (size_t)NTOK * EMB);       // 3072 floats

    cvt_kernel<<<2048, 256, 0, stream>>>(src, src_bf, NTOK * EMB / 4);
    cvt_kernel<<<512, 256, 0, stream>>>(Wq, wqkv,                       EMB * EMB / 4);
    cvt_kernel<<<512, 256, 0, stream>>>(Wk, wqkv + (size_t)EMB * EMB,   EMB * EMB / 4);
    cvt_kernel<<<512, 256, 0, stream>>>(Wv, wqkv + (size_t)2 * EMB * EMB, EMB * EMB / 4);
    cvt_kernel<<<512, 256, 0, stream>>>(Wo, wo_bf, EMB * EMB / 4);
    bias_cat_kernel<<<12, 256, 0, stream>>>(bq, bk, bv, bias_cat);

    // fused QKV projection: [16384][3072] = src_bf * [3072][1024]^T
    gemm256<unsigned short><<<dim3(64 * 12), 512, 0, stream>>>(
        src_bf, wqkv, bias_cat, qkv, EMB, 3 * EMB, 64);

    attn_kernel<<<NTOK / 4, 256, 0, stream>>>(qkv, ab);

    // output projection: [16384][1024]
    gemm256<float><<<dim3(64 * 4), 512, 0, stream>>>(
        ab, wo_bf, bo, out, EMB, EMB, 64);
}